// Round 7
// baseline (411.250 us; speedup 1.0000x reference)
//
#include <hip/hip_runtime.h>

#define N_NODES 100000
#define N_EDGES 3200000
#define BN_EPS 1e-5f

#define BLK_NODES 128            // nodes per bin block
#define NBLK 782                 // ceil(100000/128)
#define CHUNK 16384              // edges per fill workgroup (196 wgs; long runs
                                 // -> L2 write-combining; 4096 regressed 2x)
#define NW ((N_EDGES + CHUNK - 1) / CHUNK)  // 196
#define BCAP 4480                // words per bin (mean 4094, ~6 sigma)
#define CUR_PAD 16               // ints per cursor -> 64B
#define NSLICE 32                // stat partial slices

typedef unsigned int uint;
typedef unsigned short ushort;
typedef _Float16 half_t;
typedef __attribute__((ext_vector_type(8))) _Float16 h8v;  // 8 f16 (4 VGPRs)
typedef __attribute__((ext_vector_type(4))) float f4v;     // MFMA C/D

__device__ inline float bf_lo(uint u) { return __uint_as_float(u << 16); }
__device__ inline float bf_hi(uint u) { return __uint_as_float(u & 0xffff0000u); }
__device__ inline float h_lo(uint u) {
    union { ushort s; half_t h; } r; r.s = (ushort)(u & 0xffffu); return (float)r.h;
}
__device__ inline float h_hi(uint u) {
    union { ushort s; half_t h; } r; r.s = (ushort)(u >> 16); return (float)r.h;
}
__device__ inline ushort f2bf(float a) {
    uint ua = __float_as_uint(a); ua += 0x7fffu + ((ua >> 16) & 1u);
    return (ushort)(ua >> 16);
}
__device__ inline ushort f2h(float a) {
    union { half_t h; ushort u; } r;
    r.h = (half_t)a;
    return r.u;
}
__device__ inline uint packh2(float a, float b) {
    return (uint)f2h(a) | ((uint)f2h(b) << 16);
}
__device__ inline h8v loadH(const ushort* p) {
    union { uint4 q; h8v f; } r;
    r.q = *(const uint4*)p;
    return r.f;
}
__device__ inline h8v loadHh(const half_t* p) {
    union { uint4 q; h8v f; } r;
    r.q = *(const uint4*)p;
    return r.f;
}
__device__ inline f4v mfma16(h8v a, h8v b, f4v c) {
    return __builtin_amdgcn_mfma_f32_16x16x32_f16(a, b, c, 0, 0, 0);
}

// Depth-3 col-state prefetch for the k_layer0M gather pipeline.
#define FETCH_COLS(rr, st, dg, mx, wv, wv2)                                   \
    {                                                                         \
        int _r = (rr);                                                        \
        st = __shfl(myStart, 2 * _r + hl, 64);                                \
        dg = __shfl(myDeg, 2 * _r + hl, 64);                                  \
        int _dA = __shfl(myDeg, 2 * _r, 64);                                  \
        int _dB = __shfl(myDeg, 2 * _r + 1, 64);                              \
        mx = max(_dA, _dB);                                                   \
        int _e1 = min(l5, dg - 1); _e1 = _e1 < 0 ? 0 : _e1;                   \
        int _e2 = min(32 + l5, dg - 1); _e2 = _e2 < 0 ? 0 : _e2;              \
        wv = col[st + _e1];                                                   \
        wv2 = col[st + _e2];                                                  \
    }

// ---------------------------------------------------------------------------
// Build h0 [N,16] in f16: [x0, x1, emb[label][0..7], 0 x6].
// Block 0 additionally converts/transposes all weights to f16 (merged k_wcvt).
__global__ __launch_bounds__(256) void k_h0(const float* __restrict__ x,
                                            const int* __restrict__ lab,
                                            const float* __restrict__ emb,
                                            ushort* __restrict__ h0,
                                            const float* __restrict__ W1_0,
                                            const float* __restrict__ W2_0,
                                            const float* __restrict__ W1_s,
                                            const float* __restrict__ W2_s,
                                            ushort* __restrict__ W0t,
                                            ushort* __restrict__ W20t,
                                            ushort* __restrict__ Wst, int n) {
    int i = blockIdx.x * blockDim.x + threadIdx.x;
    if (i < n) {
        float v[16];
        v[0] = x[2 * i];
        v[1] = x[2 * i + 1];
        int L = lab[i];
#pragma unroll
        for (int k = 0; k < 8; k++) v[2 + k] = emb[L * 8 + k];
#pragma unroll
        for (int k = 10; k < 16; k++) v[k] = 0.f;
        uint o8[8];
#pragma unroll
        for (int k = 0; k < 8; k++) o8[k] = packh2(v[2 * k], v[2 * k + 1]);
        uint4* o = (uint4*)(h0 + (size_t)i * 16);
        o[0] = uint4{o8[0], o8[1], o8[2], o8[3]};
        o[1] = uint4{o8[4], o8[5], o8[6], o8[7]};
    }
    if (blockIdx.x == 0) {
        int t = threadIdx.x;
        for (int j = t; j < 64 * 32; j += 256) {       // W0t [64][32], K padded
            int nn = j >> 5, k = j & 31;
            W0t[j] = (k < 10) ? f2h(W1_0[k * 64 + nn]) : (ushort)0;
        }
        for (int j = t; j < 4096; j += 256) {          // W20t [64][64]
            int nn = j >> 6, k = j & 63;
            W20t[j] = f2h(W2_0[k * 64 + nn]);
        }
        for (int l = 0; l < 2; l++) {
            const float* w1 = W1_s + l * 4096;
            const float* w2 = W2_s + l * 4096;
            for (int j = t; j < 4096; j += 256) {
                int nn = j >> 6, k = j & 63;
                Wst[l * 8192 + j] = f2h(w1[k * 64 + nn]);
                Wst[l * 8192 + 4096 + j] = f2h(w2[k * 64 + nn]);
            }
        }
    }
}

// ---------------------------------------------------------------------------
// LDS-binned fill: count chunk into 782 bins, reserve contiguous runs
// (1 atomic per wg-bin), stream words into runs. CHUNK=16384: ~21-word runs
// assemble full lines in L2 (write amp ~2x); smaller chunks regress (r17).
__global__ __launch_bounds__(256) void k_fill(const int* __restrict__ src,
                                              const int* __restrict__ dst,
                                              int* __restrict__ gcur,
                                              int* __restrict__ bucket) {
    __shared__ int cnt[NBLK];
    __shared__ int off[NBLK];
    int t = threadIdx.x;
    for (int b = t; b < NBLK; b += 256) cnt[b] = 0;
    __syncthreads();
    int my0 = blockIdx.x * CHUNK + t * 64;
    for (int k = 0; k < 64; k += 4) {
        int e = my0 + k;
        if (e + 3 < N_EDGES) {
            int4 d4 = *(const int4*)(dst + e);
            atomicAdd(&cnt[d4.x >> 7], 1);
            atomicAdd(&cnt[d4.y >> 7], 1);
            atomicAdd(&cnt[d4.z >> 7], 1);
            atomicAdd(&cnt[d4.w >> 7], 1);
        } else {
#pragma unroll
            for (int kk = 0; kk < 4; kk++) {
                int ee = e + kk;
                if (ee < N_EDGES) atomicAdd(&cnt[dst[ee] >> 7], 1);
            }
        }
    }
    __syncthreads();
    for (int b = t; b < NBLK; b += 256) {
        int c = cnt[b];
        off[b] = (c > 0) ? atomicAdd(&gcur[b * CUR_PAD], c) : 0;
    }
    __syncthreads();
    for (int k = 0; k < 64; k += 4) {
        int e = my0 + k;
        if (e + 3 < N_EDGES) {
            int4 d4 = *(const int4*)(dst + e);
            int4 s4 = *(const int4*)(src + e);
            int dd[4] = {d4.x, d4.y, d4.z, d4.w};
            int ss[4] = {s4.x, s4.y, s4.z, s4.w};
#pragma unroll
            for (int kk = 0; kk < 4; kk++) {
                int b = dd[kk] >> 7;
                int p = atomicAdd(&off[b], 1);
                if (p < BCAP)
                    bucket[(size_t)b * BCAP + p] = ((dd[kk] & 127) << 17) | ss[kk];
            }
        } else {
#pragma unroll
            for (int kk = 0; kk < 4; kk++) {
                int ee = e + kk;
                if (ee < N_EDGES) {
                    int d = dst[ee], s = src[ee];
                    int b = d >> 7;
                    int p = atomicAdd(&off[b], 1);
                    if (p < BCAP)
                        bucket[(size_t)b * BCAP + p] = ((d & 127) << 17) | s;
                }
            }
        }
    }
}

// ---------------------------------------------------------------------------
// Per-block counting sort -> per-node-contiguous col2 + nodeoff = (start,deg)
__global__ __launch_bounds__(256) void k_sort(const int* __restrict__ gcur,
                                              const int* __restrict__ bucket,
                                              int* __restrict__ col2,
                                              int2* __restrict__ nodeoff, int n) {
    __shared__ int cnt[BLK_NODES];
    __shared__ int scn[BLK_NODES];
    __shared__ int cur[BLK_NODES];
    int t = threadIdx.x;
    int blk = blockIdx.x;
    if (t < BLK_NODES) cnt[t] = 0;
    __syncthreads();
    int cc = min(gcur[blk * CUR_PAD], BCAP);
    const int* bb = bucket + (size_t)blk * BCAP;
    for (int i = t; i < cc; i += 256) atomicAdd(&cnt[bb[i] >> 17], 1);
    __syncthreads();
    if (t < BLK_NODES) scn[t] = cnt[t];
    __syncthreads();
#pragma unroll
    for (int off = 1; off < BLK_NODES; off <<= 1) {
        int v = (t >= off && t < BLK_NODES) ? scn[t - off] : 0;
        __syncthreads();
        if (t < BLK_NODES) scn[t] += v;
        __syncthreads();
    }
    if (t < BLK_NODES) {
        int start = scn[t] - cnt[t];
        cur[t] = start;
        int node = blk * BLK_NODES + t;
        if (node < n) nodeoff[node] = int2{blk * BCAP + start, cnt[t]};
    }
    __syncthreads();
    int* out = col2 + (size_t)blk * BCAP;
    for (int i = t; i < cc; i += 256) {
        int w = bb[i];
        int p = atomicAdd(&cur[w >> 17], 1);
        out[p] = w & 0x1FFFF;
    }
}

// ---------------------------------------------------------------------------
// Layer 0: block = 4 waves = 64 nodes. Gather16 over f16 h0 (32B rows;
// 2 nodes/wave x 8 rounds, depth-3 col prefetch) into wave-private f16 LDS,
// then f16 MFMA MLP + stats + f16 store.  (unchanged this round)
__global__ __launch_bounds__(256, 4) void k_layer0M(const ushort* __restrict__ h0,
                                                    const int2* __restrict__ nodeoff,
                                                    const int* __restrict__ col,
                                                    const float* __restrict__ epsp,
                                                    const ushort* __restrict__ W0t,
                                                    const float* __restrict__ b1,
                                                    const ushort* __restrict__ W20t,
                                                    const float* __restrict__ b2,
                                                    ushort* __restrict__ hraw,
                                                    float* __restrict__ part_out) {
    __shared__ half_t buf[4][16][72];   // comb (cols 0..31) then h1 (cols 0..63)
    int t = threadIdx.x, w = t >> 6, lane = t & 63;
    int base = blockIdx.x * 64 + w * 16;
    float ep = 1.f + *epsp;
    int hl = lane >> 5, l5 = lane & 31;
    int q = l5 & 3, g = l5 >> 2;  // 8 groups x 4 lanes per half
    const uint* hb = (const uint*)h0;  // row = 8 uints (16 f16)

    int nj = base + (lane & 15);
    int2 no2 = nodeoff[nj];  // padded past N (zero-init)
    bool njv = nj < N_NODES;
    int myStart = njv ? no2.x : 0;
    int myDeg = njv ? no2.y : 0;

    int stC, dgC, mxC, wvC, wv2C;
    int stN, dgN, mxN, wvN, wv2N;
    FETCH_COLS(0, stC, dgC, mxC, wvC, wv2C);
    FETCH_COLS(1, stN, dgN, mxN, wvN, wv2N);

    for (int r = 0; r < 8; r++) {
        int stNN, dgNN, mxNN, wvNN, wv2NN;
        FETCH_COLS(min(r + 2, 7), stNN, dgNN, mxNN, wvNN, wv2NN);
        int deg = dgC, mx = mxC;
        float ac[4] = {0.f, 0.f, 0.f, 0.f};
        if (mx > 0) {
            int idx[4];
#pragma unroll
            for (int i = 0; i < 4; i++) idx[i] = __shfl(wvC, (hl << 5) + g + 8 * i, 64);
            uint2 rows[4];
#pragma unroll
            for (int i = 0; i < 4; i++)
                rows[i] = *(const uint2*)(hb + (size_t)idx[i] * 8 + q * 2);
#pragma unroll
            for (int i = 0; i < 4; i++) {
                float m = (g + 8 * i < deg) ? 1.f : 0.f;
                ac[0] = fmaf(m, h_lo(rows[i].x), ac[0]);
                ac[1] = fmaf(m, h_hi(rows[i].x), ac[1]);
                ac[2] = fmaf(m, h_lo(rows[i].y), ac[2]);
                ac[3] = fmaf(m, h_hi(rows[i].y), ac[3]);
            }
            if (mx > 32) {
                int idx2[4];
#pragma unroll
                for (int i = 0; i < 4; i++) idx2[i] = __shfl(wv2C, (hl << 5) + g + 8 * i, 64);
                uint2 rows2[4];
#pragma unroll
                for (int i = 0; i < 4; i++)
                    rows2[i] = *(const uint2*)(hb + (size_t)idx2[i] * 8 + q * 2);
#pragma unroll
                for (int i = 0; i < 4; i++) {
                    float m = (32 + g + 8 * i < deg) ? 1.f : 0.f;
                    ac[0] = fmaf(m, h_lo(rows2[i].x), ac[0]);
                    ac[1] = fmaf(m, h_hi(rows2[i].x), ac[1]);
                    ac[2] = fmaf(m, h_lo(rows2[i].y), ac[2]);
                    ac[3] = fmaf(m, h_hi(rows2[i].y), ac[3]);
                }
                for (int e = 64 + g; e < deg; e += 8) {
                    uint2 v = *(const uint2*)(hb + (size_t)col[stC + e] * 8 + q * 2);
                    ac[0] += h_lo(v.x); ac[1] += h_hi(v.x);
                    ac[2] += h_lo(v.y); ac[3] += h_hi(v.y);
                }
            }
        }
#pragma unroll
        for (int o = 4; o < 32; o <<= 1) {
#pragma unroll
            for (int k = 0; k < 4; k++) ac[k] += __shfl_xor(ac[k], o, 64);
        }
        int node = base + 2 * r + hl;
        bool valid = node < N_NODES;
        int nodeC = valid ? node : 0;
        float vm = valid ? ep : 0.f;
        uint2 sv = *(const uint2*)(hb + (size_t)nodeC * 8 + q * 2);
        ac[0] = fmaf(vm, h_lo(sv.x), ac[0]);
        ac[1] = fmaf(vm, h_hi(sv.x), ac[1]);
        ac[2] = fmaf(vm, h_lo(sv.y), ac[2]);
        ac[3] = fmaf(vm, h_hi(sv.y), ac[3]);
        if (!valid) { ac[0] = ac[1] = ac[2] = ac[3] = 0.f; }
        if (g == 0) {
            int nl = 2 * r + hl;
            *(uint2*)&buf[w][nl][q * 4] = uint2{packh2(ac[0], ac[1]), packh2(ac[2], ac[3])};
            *(uint2*)&buf[w][nl][16 + q * 4] = uint2{0u, 0u};
        }
        stC = stN; dgC = dgN; mxC = mxN; wvC = wvN; wv2C = wv2N;
        stN = stNN; dgN = dgNN; mxN = mxNN; wvN = wvNN; wv2N = wv2NN;
    }
    // ---- f16 MFMA MLP (wave-synchronous LDS; no barrier; buf aliased) ----
    int mr = lane & 15, kq = lane >> 4, nc = lane & 15;
    h8v A0 = loadHh(&buf[w][mr][kq * 8]);
#pragma unroll
    for (int nt = 0; nt < 4; nt++) {
        float bb = b1[nt * 16 + nc];
        f4v c = {bb, bb, bb, bb};
        c = mfma16(A0, loadH(W0t + (nt * 16 + nc) * 32 + kq * 8), c);
#pragma unroll
        for (int r2 = 0; r2 < 4; r2++)
            buf[w][kq * 4 + r2][nt * 16 + nc] = (half_t)fmaxf(c[r2], 0.f);
    }
    h8v P0 = loadHh(&buf[w][mr][kq * 8]);
    h8v P1 = loadHh(&buf[w][mr][32 + kq * 8]);
    float sA[4], sB[4];
#pragma unroll
    for (int nt = 0; nt < 4; nt++) { sA[nt] = 0.f; sB[nt] = 0.f; }
#pragma unroll
    for (int nt = 0; nt < 4; nt++) {
        float bb = b2[nt * 16 + nc];
        f4v c = {bb, bb, bb, bb};
        c = mfma16(P0, loadH(W20t + (nt * 16 + nc) * 64 + kq * 8), c);
        c = mfma16(P1, loadH(W20t + (nt * 16 + nc) * 64 + 32 + kq * 8), c);
#pragma unroll
        for (int r2 = 0; r2 < 4; r2++) {
            int node = base + kq * 4 + r2;
            float vv = fmaxf(c[r2], 0.f);
            if (node < N_NODES) {
                sA[nt] += vv;
                sB[nt] = fmaf(vv, vv, sB[nt]);
                hraw[(size_t)node * 64 + nt * 16 + nc] = f2h(vv);
            }
        }
    }
#pragma unroll
    for (int o = 16; o < 64; o <<= 1) {
#pragma unroll
        for (int nt = 0; nt < 4; nt++) {
            sA[nt] += __shfl_xor(sA[nt], o, 64);
            sB[nt] += __shfl_xor(sB[nt], o, 64);
        }
    }
    if (kq == 0) {
        float* pp = part_out + (blockIdx.x & (NSLICE - 1)) * 128;
#pragma unroll
        for (int nt = 0; nt < 4; nt++) {
            atomicAdd(&pp[nt * 16 + nc], sA[nt]);
            atomicAdd(&pp[64 + nt * 16 + nc], sB[nt]);
        }
    }
}

// ---------------------------------------------------------------------------
// Activation pass: act = f16(relu(h*sc+sh)), h stored f16, BN from partials.
__global__ __launch_bounds__(256) void k_act(const ushort* __restrict__ hraw,
                                             const float* __restrict__ part,
                                             const float* __restrict__ gamma,
                                             const float* __restrict__ beta,
                                             ushort* __restrict__ act, float invn) {
    __shared__ float st[128];
    __shared__ float sc[64], sh[64];
    int t = threadIdx.x;
    if (t < 128) {
        float S = 0.f;
#pragma unroll 8
        for (int s = 0; s < NSLICE; s++) S += part[s * 128 + t];
        st[t] = S;
    }
    __syncthreads();
    if (t < 64) {
        float mu = st[t] * invn;
        float var = fmaxf(st[64 + t] * invn - mu * mu, 0.f);
        float s = gamma[t] * rsqrtf(var + BN_EPS);
        sc[t] = s;
        sh[t] = beta[t] - mu * s;
    }
    __syncthreads();
    int base = (blockIdx.x * 256 + t) * 4;
    int f0 = base & 63;
    uint2 hv = *(const uint2*)(hraw + base);
    float a0 = fmaxf(fmaf(h_lo(hv.x), sc[f0 + 0], sh[f0 + 0]), 0.f);
    float a1 = fmaxf(fmaf(h_hi(hv.x), sc[f0 + 1], sh[f0 + 1]), 0.f);
    float a2 = fmaxf(fmaf(h_lo(hv.y), sc[f0 + 2], sh[f0 + 2]), 0.f);
    float a3 = fmaxf(fmaf(h_hi(hv.y), sc[f0 + 3], sh[f0 + 3]), 0.f);
    uint2 o;
    o.x = packh2(a0, a1);
    o.y = packh2(a2, a3);
    *(uint2*)(act + base) = o;
}

// ---------------------------------------------------------------------------
// Layers 1/2 (MFMA-aggregate, tr-read B, chunk-pipelined): block = 4 waves;
// wave = 16 nodes. D += A*B per 32-edge chunk (A = segment indicator,
// B = gathered act rows staged as 4 x [32 edge][16 feat] f16 tiles,
// tr-read B-fragment assembly -- layout/semantics verified in R6).
// NEW: depth-2 chunk pipeline. Chunks j (staging), j+1 (in regs), j+2
// (loads in flight) live simultaneously -> ds_write of chunk j gets a
// COUNTED vmcnt (5 newer loads stay in flight), hiding ~1.5 iterations of
// L2/L3 gather latency. R6 evidence: DS-op cut (36->12) and VALU cut
// changed nothing -> critical path is the serial gather->stage->read->MFMA
// chain at 64B/lane in flight; this triples in-flight bytes.
// sched_barrier(0) after prefetch issue pins the loads (R0 lesson: the
// compiler otherwise sinks them to the use point and un-pipelines).
__global__ __launch_bounds__(256, 4) void k_layerM(const uint* __restrict__ actin,
                                                   const int2* __restrict__ nodeoff,
                                                   const int* __restrict__ col,
                                                   const float* __restrict__ epsp,
                                                   const ushort* __restrict__ W1t,
                                                   const float* __restrict__ b1,
                                                   const ushort* __restrict__ W2t,
                                                   const float* __restrict__ b2,
                                                   ushort* __restrict__ hraw,
                                                   float* __restrict__ part_out) {
    __shared__ ushort stg[4][2048];     // per-wave 4 x [32 edge][16 feat] (4 KB)
    __shared__ half_t buf[4][16][72];   // comb then h1 (aliased, wave-private)
    int t = threadIdx.x, w = t >> 6, lane = t & 63;
    int wbase = blockIdx.x * 64 + w * 16;
    float ep = 1.f + *epsp;
    int nc = lane & 15, kq = lane >> 4;
    const ushort* au = (const ushort*)actin;

    // per-lane segment bounds for node m = nc (pad zero-init + njv guard)
    int nj = wbase + nc;
    int2 no2 = nodeoff[nj];
    bool njv = nj < N_NODES;
    int sm = njv ? no2.x : 0;
    int dm = njv ? no2.y : 0;
    int se = sm + dm;

    int e0 = __shfl(sm, 0, 64);          // wave's first edge (abs col2 index)
    int eEnd = __shfl(se, 15, 64);       // one past last edge
    e0 = max(0, min(e0, NBLK * BCAP - 1));
    int T = max(eEnd - e0, 0);
    int eLast = min(e0 + max(T - 1, 0), NBLK * BCAP - 1);
    int C = min((max(T, 1) + 31) >> 5, (BCAP + 31) >> 5);  // 32-edge chunks

    // C init: (1+eps) * self row. lane holds D[m=kq*4+r][n=nt*16+nc]
    f4v acc[4];
#pragma unroll
    for (int nt = 0; nt < 4; nt++) {
#pragma unroll
        for (int r = 0; r < 4; r++) {
            int nd = wbase + kq * 4 + r;
            float vm = (nd < N_NODES) ? ep : 0.f;
            int ndc = (nd < N_NODES) ? nd : 0;
            acc[nt][r] = vm * h_lo(au[(size_t)ndc * 64 + nt * 16 + nc]);
        }
    }

    // stage side: lane (s5, hh) stages edge s5, feature-half hh (8 feats/16B
    // per tile). tr-read side: 8B-chunk contribution address per lane.
    int s5 = lane & 31, hh = lane >> 5;
    char* tb = (char*)&stg[w][0];
    char* lw = tb + s5 * 32 + hh * 16;
    uint rdaddr = (uint)(size_t)tb + (uint)(kq * 256 + nc * 8);

    // prologue: cols + row-loads for chunks 0,1; col for chunk 2
    int c0 = min(col[min(e0 + s5, eLast)] & 0x1FFFF, N_NODES - 1);
    int c1 = min(col[min(e0 + 32 + s5, eLast)] & 0x1FFFF, N_NODES - 1);
    int c2 = min(col[min(e0 + 64 + s5, eLast)] & 0x1FFFF, N_NODES - 1);
    uint4 a0, a1, a2, a3, b0v, b1v, b2v, b3v;
    {
        const ushort* gs = au + (size_t)c0 * 64 + hh * 8;
        a0 = *(const uint4*)(gs);
        a1 = *(const uint4*)(gs + 16);
        a2 = *(const uint4*)(gs + 32);
        a3 = *(const uint4*)(gs + 48);
    }
    {
        const ushort* gs = au + (size_t)c1 * 64 + hh * 8;
        b0v = *(const uint4*)(gs);
        b1v = *(const uint4*)(gs + 16);
        b2v = *(const uint4*)(gs + 32);
        b3v = *(const uint4*)(gs + 48);
    }

    for (int j = 0; j < C; j++) {
        // stage chunk j (counted vmcnt: only a0..a3's loads must land;
        // chunk j+1's rows + j+2's col stay in flight across this wait)
        *(uint4*)(lw) = a0;
        *(uint4*)(lw + 1024) = a1;
        *(uint4*)(lw + 2048) = a2;
        *(uint4*)(lw + 3072) = a3;
        // issue chunk j+2 gather; prefetch chunk j+3 col
        uint4 n0, n1, n2, n3;
        {
            const ushort* gs = au + (size_t)c2 * 64 + hh * 8;
            n0 = *(const uint4*)(gs);
            n1 = *(const uint4*)(gs + 16);
            n2 = *(const uint4*)(gs + 32);
            n3 = *(const uint4*)(gs + 48);
        }
        c2 = min(col[min(e0 + (j + 3) * 32 + s5, eLast)] & 0x1FFFF, N_NODES - 1);
        __builtin_amdgcn_sched_barrier(0);  // pin prefetch issue (anti-sink)
        // A fragment: f16 1.0 where edge k (= kq*8+jj) lies in node nc's range
        int eb = e0 + j * 32 + kq * 8;
        union { uint u[4]; h8v v; } aw;
#pragma unroll
        for (int p = 0; p < 4; p++) {
            int ea = eb + 2 * p;
            uint lo = (ea >= sm && ea < se) ? 0x3C00u : 0u;
            uint hi = (ea + 1 >= sm && ea + 1 < se) ? 0x3C000000u : 0u;
            aw.u[p] = lo | hi;
        }
        // B fragments: 2 x ds_read_b64_tr_b16 per tile (rows +0..3 / +4..7)
        uint2 p0, p1, p2, p3, p4, p5, p6, p7;
        asm volatile(
            "ds_read_b64_tr_b16 %0, %8 offset:0\n\t"
            "ds_read_b64_tr_b16 %1, %8 offset:128\n\t"
            "ds_read_b64_tr_b16 %2, %8 offset:1024\n\t"
            "ds_read_b64_tr_b16 %3, %8 offset:1152\n\t"
            "ds_read_b64_tr_b16 %4, %8 offset:2048\n\t"
            "ds_read_b64_tr_b16 %5, %8 offset:2176\n\t"
            "ds_read_b64_tr_b16 %6, %8 offset:3072\n\t"
            "ds_read_b64_tr_b16 %7, %8 offset:3200\n\t"
            "s_waitcnt lgkmcnt(0)"
            : "=&v"(p0), "=&v"(p1), "=&v"(p2), "=&v"(p3),
              "=&v"(p4), "=&v"(p5), "=&v"(p6), "=&v"(p7)
            : "v"(rdaddr)
            : "memory");
        __builtin_amdgcn_sched_barrier(0);
        union { uint2 q[2]; h8v v; } f0, f1, f2, f3;
        f0.q[0] = p0; f0.q[1] = p1;
        f1.q[0] = p2; f1.q[1] = p3;
        f2.q[0] = p4; f2.q[1] = p5;
        f3.q[0] = p6; f3.q[1] = p7;
        acc[0] = mfma16(aw.v, f0.v, acc[0]);
        acc[1] = mfma16(aw.v, f1.v, acc[1]);
        acc[2] = mfma16(aw.v, f2.v, acc[2]);
        acc[3] = mfma16(aw.v, f3.v, acc[3]);
        // rotate pipeline regs
        a0 = b0v; a1 = b1v; a2 = b2v; a3 = b3v;
        b0v = n0; b1v = n1; b2v = n2; b3v = n3;
    }

    // comb -> buf (f16): D[m][n] -> buf[w][m][n]
#pragma unroll
    for (int nt = 0; nt < 4; nt++) {
#pragma unroll
        for (int r2 = 0; r2 < 4; r2++)
            buf[w][kq * 4 + r2][nt * 16 + nc] = (half_t)acc[nt][r2];
    }

    // ---- f16 MFMA MLP (wave-synchronous LDS; no barrier; buf aliased) ----
    int mr = lane & 15;
    h8v A0 = loadHh(&buf[w][mr][kq * 8]);
    h8v A1 = loadHh(&buf[w][mr][32 + kq * 8]);
#pragma unroll
    for (int nt = 0; nt < 4; nt++) {
        float bb = b1[nt * 16 + nc];
        f4v c = {bb, bb, bb, bb};
        c = mfma16(A0, loadH(W1t + (nt * 16 + nc) * 64 + kq * 8), c);
        c = mfma16(A1, loadH(W1t + (nt * 16 + nc) * 64 + 32 + kq * 8), c);
#pragma unroll
        for (int r2 = 0; r2 < 4; r2++)
            buf[w][kq * 4 + r2][nt * 16 + nc] = (half_t)fmaxf(c[r2], 0.f);
    }
    h8v P0 = loadHh(&buf[w][mr][kq * 8]);
    h8v P1 = loadHh(&buf[w][mr][32 + kq * 8]);
    float sA[4], sB[4];
#pragma unroll
    for (int nt = 0; nt < 4; nt++) { sA[nt] = 0.f; sB[nt] = 0.f; }
#pragma unroll
    for (int nt = 0; nt < 4; nt++) {
        float bb = b2[nt * 16 + nc];
        f4v c = {bb, bb, bb, bb};
        c = mfma16(P0, loadH(W2t + (nt * 16 + nc) * 64 + kq * 8), c);
        c = mfma16(P1, loadH(W2t + (nt * 16 + nc) * 64 + 32 + kq * 8), c);
#pragma unroll
        for (int r2 = 0; r2 < 4; r2++) {
            int node = wbase + kq * 4 + r2;
            float vv = fmaxf(c[r2], 0.f);
            if (node < N_NODES) {
                sA[nt] += vv;
                sB[nt] = fmaf(vv, vv, sB[nt]);
                hraw[(size_t)node * 64 + nt * 16 + nc] = f2h(vv);
            }
        }
    }
#pragma unroll
    for (int o = 16; o < 64; o <<= 1) {
#pragma unroll
        for (int nt = 0; nt < 4; nt++) {
            sA[nt] += __shfl_xor(sA[nt], o, 64);
            sB[nt] += __shfl_xor(sB[nt], o, 64);
        }
    }
    if (kq == 0) {
        float* pp = part_out + (blockIdx.x & (NSLICE - 1)) * 128;
#pragma unroll
        for (int nt = 0; nt < 4; nt++) {
            atomicAdd(&pp[nt * 16 + nc], sA[nt]);
            atomicAdd(&pp[64 + nt * 16 + nc], sB[nt]);
        }
    }
}

// ---------------------------------------------------------------------------
// Final: fold BN2 partials; out[i] = bf + sum_j relu(h*sc+sh) * Wf[j]
__global__ __launch_bounds__(256) void k_out(const ushort* __restrict__ hraw,
                                             const float* __restrict__ part,
                                             const float* __restrict__ gamma,
                                             const float* __restrict__ beta,
                                             const float* __restrict__ Wf,
                                             const float* __restrict__ bfp,
                                             float* __restrict__ out, int n,
                                             float invn) {
    __shared__ float st[128];
    __shared__ float sc[64], sh[64];
    int t = threadIdx.x;
    if (t < 128) {
        float S = 0.f;
#pragma unroll 8
        for (int s = 0; s < NSLICE; s++) S += part[s * 128 + t];
        st[t] = S;
    }
    __syncthreads();
    if (t < 64) {
        float mu = st[t] * invn;
        float var = fmaxf(st[64 + t] * invn - mu * mu, 0.f);
        float s = gamma[t] * rsqrtf(var + BN_EPS);
        sc[t] = s;
        sh[t] = beta[t] - mu * s;
    }
    __syncthreads();
    int i = blockIdx.x * blockDim.x + threadIdx.x;
    if (i >= n) return;
    float acc = *bfp;
    const uint2* h2 = (const uint2*)(hraw + (size_t)i * 64);
#pragma unroll
    for (int qq = 0; qq < 16; qq++) {
        uint2 v = h2[qq];
        int j = qq * 4;
        acc = fmaf(fmaxf(fmaf(h_lo(v.x), sc[j + 0], sh[j + 0]), 0.f), Wf[j + 0], acc);
        acc = fmaf(fmaxf(fmaf(h_hi(v.x), sc[j + 1], sh[j + 1]), 0.f), Wf[j + 1], acc);
        acc = fmaf(fmaxf(fmaf(h_lo(v.y), sc[j + 2], sh[j + 2]), 0.f), Wf[j + 2], acc);
        acc = fmaf(fmaxf(fmaf(h_hi(v.y), sc[j + 3], sh[j + 3]), 0.f), Wf[j + 3], acc);
    }
    out[i] = acc;
}

// ---------------------------------------------------------------------------
extern "C" void kernel_launch(void* const* d_in, const int* in_sizes, int n_in,
                              void* d_out, int out_size, void* d_ws, size_t ws_size,
                              hipStream_t stream) {
    const float* x      = (const float*)d_in[0];
    const int*   lab    = (const int*)d_in[1];
    const int*   edge   = (const int*)d_in[2];  // [2][E]: src then dst
    const float* emb    = (const float*)d_in[3];
    const float* W1_0   = (const float*)d_in[4];
    const float* b1_0   = (const float*)d_in[5];
    const float* W2_0   = (const float*)d_in[6];
    const float* b2_0   = (const float*)d_in[7];
    const float* eps_0  = (const float*)d_in[8];
    const float* gamma_0= (const float*)d_in[9];
    const float* beta_0 = (const float*)d_in[10];
    const float* W1_s   = (const float*)d_in[11];
    const float* b1_s   = (const float*)d_in[12];
    const float* W2_s   = (const float*)d_in[13];
    const float* b2_s   = (const float*)d_in[14];
    const float* eps_s  = (const float*)d_in[15];
    const float* gamma_s= (const float*)d_in[16];
    const float* beta_s = (const float*)d_in[17];
    const float* Wf     = (const float*)d_in[18];
    const float* bf     = (const float*)d_in[19];

    const int N = N_NODES, E = N_EDGES;
    const int* srcp = edge;
    const int* dstp = edge + E;

    char* p = (char*)d_ws;
    auto alloc = [&](size_t bytes) {
        void* r = (void*)p;
        p += (bytes + 255) & ~(size_t)255;
        return r;
    };
    int* bucket  = (int*)alloc((size_t)NBLK * BCAP * 4);      // 14.0 MB
    int* col2    = (int*)alloc((size_t)NBLK * BCAP * 4);      // 14.0 MB
    int* gcur    = (int*)alloc((size_t)NBLK * CUR_PAD * 4);   // 50 KB
    int* nodeoff = (int*)alloc((size_t)(N + 64) * 8);         // padded for OOB reads
    ushort* hraw = (ushort*)alloc((size_t)N * 64 * 2);        // 12.8 MB (f16)
    ushort* act  = (ushort*)alloc((size_t)N * 64 * 2);        // 12.8 MB (f16)
    ushort* h0   = (ushort*)alloc((size_t)N * 16 * 2);        //  3.2 MB (f16)
    float* parts = (float*)alloc(3 * NSLICE * 128 * 4);       // 48 KB
    ushort* W0t  = (ushort*)alloc(64 * 32 * 2);
    ushort* W20t = (ushort*)alloc(4096 * 2);
    ushort* Wst  = (ushort*)alloc(2 * 8192 * 2);

    hipMemsetAsync(gcur, 0, (size_t)NBLK * CUR_PAD * 4, stream);
    hipMemsetAsync(parts, 0, 3 * NSLICE * 128 * 4, stream);
    hipMemsetAsync(nodeoff + 2 * (size_t)N, 0, 64 * 8, stream);  // zero pad tail

    const int TB = 256;
    const int gN = (N + TB - 1) / TB;
    const int gM = (N + 63) / 64;  // 1563 blocks, 64 nodes each
    const int gA = N * 64 / 1024;
    const float invn = 1.0f / (float)N;

    k_h0<<<gN, TB, 0, stream>>>(x, lab, emb, h0, W1_0, W2_0, W1_s, W2_s,
                                W0t, W20t, Wst, N);
    k_fill<<<NW, TB, 0, stream>>>(srcp, dstp, gcur, bucket);
    k_sort<<<NBLK, TB, 0, stream>>>(gcur, bucket, col2, (int2*)nodeoff, N);

    // ---- Layer 0 ----
    k_layer0M<<<gM, TB, 0, stream>>>(h0, (const int2*)nodeoff, col2, eps_0, W0t,
                                     b1_0, W20t, b2_0, hraw,
                                     parts + 0 * NSLICE * 128);
    k_act<<<gA, TB, 0, stream>>>(hraw, parts + 0 * NSLICE * 128, gamma_0, beta_0,
                                 act, invn);

    // ---- Layer 1 ----
    k_layerM<<<gM, TB, 0, stream>>>((const uint*)act, (const int2*)nodeoff, col2,
                                    eps_s + 0, Wst + 0 * 8192, b1_s + 0 * 64,
                                    Wst + 0 * 8192 + 4096, b2_s + 0 * 64,
                                    hraw, parts + 1 * NSLICE * 128);
    k_act<<<gA, TB, 0, stream>>>(hraw, parts + 1 * NSLICE * 128, gamma_s + 0 * 64,
                                 beta_s + 0 * 64, act, invn);

    // ---- Layer 2 ----
    k_layerM<<<gM, TB, 0, stream>>>((const uint*)act, (const int2*)nodeoff, col2,
                                    eps_s + 1, Wst + 1 * 8192, b1_s + 1 * 64,
                                    Wst + 1 * 8192 + 4096, b2_s + 1 * 64,
                                    hraw, parts + 2 * NSLICE * 128);

    // ---- Output (BN2 folded from partials) ----
    k_out<<<gN, TB, 0, stream>>>(hraw, parts + 2 * NSLICE * 128,
                                 gamma_s + 1 * 64, beta_s + 1 * 64, Wf, bf,
                                 (float*)d_out, N, invn);
}

// Round 8
// 379.830 us; speedup vs baseline: 1.0827x; 1.0827x over previous
//
#include <hip/hip_runtime.h>

#define N_NODES 100000
#define N_EDGES 3200000
#define BN_EPS 1e-5f

#define BLK_NODES 128            // nodes per bin block
#define NBLK 782                 // ceil(100000/128)
#define CHUNK 16384              // edges per fill workgroup (196 wgs; long runs
                                 // -> L2 write-combining; 4096 regressed 2x)
#define NW ((N_EDGES + CHUNK - 1) / CHUNK)  // 196
#define BCAP 4480                // words per bin (mean 4094, ~6 sigma)
#define CUR_PAD 16               // ints per cursor -> 64B
#define NSLICE 32                // stat partial slices

typedef unsigned int uint;
typedef unsigned short ushort;
typedef _Float16 half_t;
typedef __attribute__((ext_vector_type(8))) _Float16 h8v;  // 8 f16 (4 VGPRs)
typedef __attribute__((ext_vector_type(4))) float f4v;     // MFMA C/D

__device__ inline float bf_lo(uint u) { return __uint_as_float(u << 16); }
__device__ inline float bf_hi(uint u) { return __uint_as_float(u & 0xffff0000u); }
__device__ inline float h_lo(uint u) {
    union { ushort s; half_t h; } r; r.s = (ushort)(u & 0xffffu); return (float)r.h;
}
__device__ inline float h_hi(uint u) {
    union { ushort s; half_t h; } r; r.s = (ushort)(u >> 16); return (float)r.h;
}
__device__ inline ushort f2bf(float a) {
    uint ua = __float_as_uint(a); ua += 0x7fffu + ((ua >> 16) & 1u);
    return (ushort)(ua >> 16);
}
__device__ inline ushort f2h(float a) {
    union { half_t h; ushort u; } r;
    r.h = (half_t)a;
    return r.u;
}
__device__ inline uint packh2(float a, float b) {
    return (uint)f2h(a) | ((uint)f2h(b) << 16);
}
__device__ inline h8v loadH(const ushort* p) {
    union { uint4 q; h8v f; } r;
    r.q = *(const uint4*)p;
    return r.f;
}
__device__ inline h8v loadHh(const half_t* p) {
    union { uint4 q; h8v f; } r;
    r.q = *(const uint4*)p;
    return r.f;
}
__device__ inline f4v mfma16(h8v a, h8v b, f4v c) {
    return __builtin_amdgcn_mfma_f32_16x16x32_f16(a, b, c, 0, 0, 0);
}

// Depth-3 col-state prefetch for the gather pipelines.
#define FETCH_COLS(rr, st, dg, mx, wv, wv2)                                   \
    {                                                                         \
        int _r = (rr);                                                        \
        st = __shfl(myStart, 2 * _r + hl, 64);                                \
        dg = __shfl(myDeg, 2 * _r + hl, 64);                                  \
        int _dA = __shfl(myDeg, 2 * _r, 64);                                  \
        int _dB = __shfl(myDeg, 2 * _r + 1, 64);                              \
        mx = max(_dA, _dB);                                                   \
        int _e1 = min(l5, dg - 1); _e1 = _e1 < 0 ? 0 : _e1;                   \
        int _e2 = min(32 + l5, dg - 1); _e2 = _e2 < 0 ? 0 : _e2;              \
        wv = col[st + _e1];                                                   \
        wv2 = col[st + _e2];                                                  \
    }

// ---------------------------------------------------------------------------
// Build h0 [N,16] in f16: [x0, x1, emb[label][0..7], 0 x6].
// Block 0 additionally converts/transposes all weights to f16 (merged k_wcvt).
__global__ __launch_bounds__(256) void k_h0(const float* __restrict__ x,
                                            const int* __restrict__ lab,
                                            const float* __restrict__ emb,
                                            ushort* __restrict__ h0,
                                            const float* __restrict__ W1_0,
                                            const float* __restrict__ W2_0,
                                            const float* __restrict__ W1_s,
                                            const float* __restrict__ W2_s,
                                            ushort* __restrict__ W0t,
                                            ushort* __restrict__ W20t,
                                            ushort* __restrict__ Wst, int n) {
    int i = blockIdx.x * blockDim.x + threadIdx.x;
    if (i < n) {
        float v[16];
        v[0] = x[2 * i];
        v[1] = x[2 * i + 1];
        int L = lab[i];
#pragma unroll
        for (int k = 0; k < 8; k++) v[2 + k] = emb[L * 8 + k];
#pragma unroll
        for (int k = 10; k < 16; k++) v[k] = 0.f;
        uint o8[8];
#pragma unroll
        for (int k = 0; k < 8; k++) o8[k] = packh2(v[2 * k], v[2 * k + 1]);
        uint4* o = (uint4*)(h0 + (size_t)i * 16);
        o[0] = uint4{o8[0], o8[1], o8[2], o8[3]};
        o[1] = uint4{o8[4], o8[5], o8[6], o8[7]};
    }
    if (blockIdx.x == 0) {
        int t = threadIdx.x;
        for (int j = t; j < 64 * 32; j += 256) {       // W0t [64][32], K padded
            int nn = j >> 5, k = j & 31;
            W0t[j] = (k < 10) ? f2h(W1_0[k * 64 + nn]) : (ushort)0;
        }
        for (int j = t; j < 4096; j += 256) {          // W20t [64][64]
            int nn = j >> 6, k = j & 63;
            W20t[j] = f2h(W2_0[k * 64 + nn]);
        }
        for (int l = 0; l < 2; l++) {
            const float* w1 = W1_s + l * 4096;
            const float* w2 = W2_s + l * 4096;
            for (int j = t; j < 4096; j += 256) {
                int nn = j >> 6, k = j & 63;
                Wst[l * 8192 + j] = f2h(w1[k * 64 + nn]);
                Wst[l * 8192 + 4096 + j] = f2h(w2[k * 64 + nn]);
            }
        }
    }
}

// ---------------------------------------------------------------------------
// LDS-binned fill: count chunk into 782 bins, reserve contiguous runs
// (1 atomic per wg-bin), stream words into runs. CHUNK=16384: ~21-word runs
// assemble full lines in L2 (write amp ~2x); smaller chunks regress (r17).
__global__ __launch_bounds__(256) void k_fill(const int* __restrict__ src,
                                              const int* __restrict__ dst,
                                              int* __restrict__ gcur,
                                              int* __restrict__ bucket) {
    __shared__ int cnt[NBLK];
    __shared__ int off[NBLK];
    int t = threadIdx.x;
    for (int b = t; b < NBLK; b += 256) cnt[b] = 0;
    __syncthreads();
    int my0 = blockIdx.x * CHUNK + t * 64;
    for (int k = 0; k < 64; k += 4) {
        int e = my0 + k;
        if (e + 3 < N_EDGES) {
            int4 d4 = *(const int4*)(dst + e);
            atomicAdd(&cnt[d4.x >> 7], 1);
            atomicAdd(&cnt[d4.y >> 7], 1);
            atomicAdd(&cnt[d4.z >> 7], 1);
            atomicAdd(&cnt[d4.w >> 7], 1);
        } else {
#pragma unroll
            for (int kk = 0; kk < 4; kk++) {
                int ee = e + kk;
                if (ee < N_EDGES) atomicAdd(&cnt[dst[ee] >> 7], 1);
            }
        }
    }
    __syncthreads();
    for (int b = t; b < NBLK; b += 256) {
        int c = cnt[b];
        off[b] = (c > 0) ? atomicAdd(&gcur[b * CUR_PAD], c) : 0;
    }
    __syncthreads();
    for (int k = 0; k < 64; k += 4) {
        int e = my0 + k;
        if (e + 3 < N_EDGES) {
            int4 d4 = *(const int4*)(dst + e);
            int4 s4 = *(const int4*)(src + e);
            int dd[4] = {d4.x, d4.y, d4.z, d4.w};
            int ss[4] = {s4.x, s4.y, s4.z, s4.w};
#pragma unroll
            for (int kk = 0; kk < 4; kk++) {
                int b = dd[kk] >> 7;
                int p = atomicAdd(&off[b], 1);
                if (p < BCAP)
                    bucket[(size_t)b * BCAP + p] = ((dd[kk] & 127) << 17) | ss[kk];
            }
        } else {
#pragma unroll
            for (int kk = 0; kk < 4; kk++) {
                int ee = e + kk;
                if (ee < N_EDGES) {
                    int d = dst[ee], s = src[ee];
                    int b = d >> 7;
                    int p = atomicAdd(&off[b], 1);
                    if (p < BCAP)
                        bucket[(size_t)b * BCAP + p] = ((d & 127) << 17) | s;
                }
            }
        }
    }
}

// ---------------------------------------------------------------------------
// Per-block counting sort -> per-node-contiguous col2 + nodeoff = (start,deg)
__global__ __launch_bounds__(256) void k_sort(const int* __restrict__ gcur,
                                              const int* __restrict__ bucket,
                                              int* __restrict__ col2,
                                              int2* __restrict__ nodeoff, int n) {
    __shared__ int cnt[BLK_NODES];
    __shared__ int scn[BLK_NODES];
    __shared__ int cur[BLK_NODES];
    int t = threadIdx.x;
    int blk = blockIdx.x;
    if (t < BLK_NODES) cnt[t] = 0;
    __syncthreads();
    int cc = min(gcur[blk * CUR_PAD], BCAP);
    const int* bb = bucket + (size_t)blk * BCAP;
    for (int i = t; i < cc; i += 256) atomicAdd(&cnt[bb[i] >> 17], 1);
    __syncthreads();
    if (t < BLK_NODES) scn[t] = cnt[t];
    __syncthreads();
#pragma unroll
    for (int off = 1; off < BLK_NODES; off <<= 1) {
        int v = (t >= off && t < BLK_NODES) ? scn[t - off] : 0;
        __syncthreads();
        if (t < BLK_NODES) scn[t] += v;
        __syncthreads();
    }
    if (t < BLK_NODES) {
        int start = scn[t] - cnt[t];
        cur[t] = start;
        int node = blk * BLK_NODES + t;
        if (node < n) nodeoff[node] = int2{blk * BCAP + start, cnt[t]};
    }
    __syncthreads();
    int* out = col2 + (size_t)blk * BCAP;
    for (int i = t; i < cc; i += 256) {
        int w = bb[i];
        int p = atomicAdd(&cur[w >> 17], 1);
        out[p] = w & 0x1FFFF;
    }
}

// ---------------------------------------------------------------------------
// Layer 0: block = 4 waves = 64 nodes. Gather16 over f16 h0 (32B rows;
// 2 nodes/wave x 8 rounds, depth-3 col prefetch) into wave-private f16 LDS,
// then f16 MFMA MLP + stats + f16 store.
__global__ __launch_bounds__(256, 4) void k_layer0M(const ushort* __restrict__ h0,
                                                    const int2* __restrict__ nodeoff,
                                                    const int* __restrict__ col,
                                                    const float* __restrict__ epsp,
                                                    const ushort* __restrict__ W0t,
                                                    const float* __restrict__ b1,
                                                    const ushort* __restrict__ W20t,
                                                    const float* __restrict__ b2,
                                                    ushort* __restrict__ hraw,
                                                    float* __restrict__ part_out) {
    __shared__ half_t buf[4][16][72];   // comb (cols 0..31) then h1 (cols 0..63)
    int t = threadIdx.x, w = t >> 6, lane = t & 63;
    int base = blockIdx.x * 64 + w * 16;
    float ep = 1.f + *epsp;
    int hl = lane >> 5, l5 = lane & 31;
    int q = l5 & 3, g = l5 >> 2;  // 8 groups x 4 lanes per half
    const uint* hb = (const uint*)h0;  // row = 8 uints (16 f16)

    int nj = base + (lane & 15);
    int2 no2 = nodeoff[nj];  // padded past N (zero-init)
    bool njv = nj < N_NODES;
    int myStart = njv ? no2.x : 0;
    int myDeg = njv ? no2.y : 0;

    int stC, dgC, mxC, wvC, wv2C;
    int stN, dgN, mxN, wvN, wv2N;
    FETCH_COLS(0, stC, dgC, mxC, wvC, wv2C);
    FETCH_COLS(1, stN, dgN, mxN, wvN, wv2N);

    for (int r = 0; r < 8; r++) {
        int stNN, dgNN, mxNN, wvNN, wv2NN;
        FETCH_COLS(min(r + 2, 7), stNN, dgNN, mxNN, wvNN, wv2NN);
        int deg = dgC, mx = mxC;
        float ac[4] = {0.f, 0.f, 0.f, 0.f};
        if (mx > 0) {
            int idx[4];
#pragma unroll
            for (int i = 0; i < 4; i++) idx[i] = __shfl(wvC, (hl << 5) + g + 8 * i, 64);
            uint2 rows[4];
#pragma unroll
            for (int i = 0; i < 4; i++)
                rows[i] = *(const uint2*)(hb + (size_t)idx[i] * 8 + q * 2);
#pragma unroll
            for (int i = 0; i < 4; i++) {
                float m = (g + 8 * i < deg) ? 1.f : 0.f;
                ac[0] = fmaf(m, h_lo(rows[i].x), ac[0]);
                ac[1] = fmaf(m, h_hi(rows[i].x), ac[1]);
                ac[2] = fmaf(m, h_lo(rows[i].y), ac[2]);
                ac[3] = fmaf(m, h_hi(rows[i].y), ac[3]);
            }
            if (mx > 32) {
                int idx2[4];
#pragma unroll
                for (int i = 0; i < 4; i++) idx2[i] = __shfl(wv2C, (hl << 5) + g + 8 * i, 64);
                uint2 rows2[4];
#pragma unroll
                for (int i = 0; i < 4; i++)
                    rows2[i] = *(const uint2*)(hb + (size_t)idx2[i] * 8 + q * 2);
#pragma unroll
                for (int i = 0; i < 4; i++) {
                    float m = (32 + g + 8 * i < deg) ? 1.f : 0.f;
                    ac[0] = fmaf(m, h_lo(rows2[i].x), ac[0]);
                    ac[1] = fmaf(m, h_hi(rows2[i].x), ac[1]);
                    ac[2] = fmaf(m, h_lo(rows2[i].y), ac[2]);
                    ac[3] = fmaf(m, h_hi(rows2[i].y), ac[3]);
                }
                for (int e = 64 + g; e < deg; e += 8) {
                    uint2 v = *(const uint2*)(hb + (size_t)col[stC + e] * 8 + q * 2);
                    ac[0] += h_lo(v.x); ac[1] += h_hi(v.x);
                    ac[2] += h_lo(v.y); ac[3] += h_hi(v.y);
                }
            }
        }
#pragma unroll
        for (int o = 4; o < 32; o <<= 1) {
#pragma unroll
            for (int k = 0; k < 4; k++) ac[k] += __shfl_xor(ac[k], o, 64);
        }
        int node = base + 2 * r + hl;
        bool valid = node < N_NODES;
        int nodeC = valid ? node : 0;
        float vm = valid ? ep : 0.f;
        uint2 sv = *(const uint2*)(hb + (size_t)nodeC * 8 + q * 2);
        ac[0] = fmaf(vm, h_lo(sv.x), ac[0]);
        ac[1] = fmaf(vm, h_hi(sv.x), ac[1]);
        ac[2] = fmaf(vm, h_lo(sv.y), ac[2]);
        ac[3] = fmaf(vm, h_hi(sv.y), ac[3]);
        if (!valid) { ac[0] = ac[1] = ac[2] = ac[3] = 0.f; }
        if (g == 0) {
            int nl = 2 * r + hl;
            *(uint2*)&buf[w][nl][q * 4] = uint2{packh2(ac[0], ac[1]), packh2(ac[2], ac[3])};
            *(uint2*)&buf[w][nl][16 + q * 4] = uint2{0u, 0u};
        }
        stC = stN; dgC = dgN; mxC = mxN; wvC = wvN; wv2C = wv2N;
        stN = stNN; dgN = dgNN; mxN = mxNN; wvN = wvNN; wv2N = wv2NN;
    }
    // ---- f16 MFMA MLP (wave-synchronous LDS; no barrier; buf aliased) ----
    int mr = lane & 15, kq = lane >> 4, nc = lane & 15;
    h8v A0 = loadHh(&buf[w][mr][kq * 8]);
#pragma unroll
    for (int nt = 0; nt < 4; nt++) {
        float bb = b1[nt * 16 + nc];
        f4v c = {bb, bb, bb, bb};
        c = mfma16(A0, loadH(W0t + (nt * 16 + nc) * 32 + kq * 8), c);
#pragma unroll
        for (int r2 = 0; r2 < 4; r2++)
            buf[w][kq * 4 + r2][nt * 16 + nc] = (half_t)fmaxf(c[r2], 0.f);
    }
    h8v P0 = loadHh(&buf[w][mr][kq * 8]);
    h8v P1 = loadHh(&buf[w][mr][32 + kq * 8]);
    float sA[4], sB[4];
#pragma unroll
    for (int nt = 0; nt < 4; nt++) { sA[nt] = 0.f; sB[nt] = 0.f; }
#pragma unroll
    for (int nt = 0; nt < 4; nt++) {
        float bb = b2[nt * 16 + nc];
        f4v c = {bb, bb, bb, bb};
        c = mfma16(P0, loadH(W20t + (nt * 16 + nc) * 64 + kq * 8), c);
        c = mfma16(P1, loadH(W20t + (nt * 16 + nc) * 64 + 32 + kq * 8), c);
#pragma unroll
        for (int r2 = 0; r2 < 4; r2++) {
            int node = base + kq * 4 + r2;
            float vv = fmaxf(c[r2], 0.f);
            if (node < N_NODES) {
                sA[nt] += vv;
                sB[nt] = fmaf(vv, vv, sB[nt]);
                hraw[(size_t)node * 64 + nt * 16 + nc] = f2h(vv);
            }
        }
    }
#pragma unroll
    for (int o = 16; o < 64; o <<= 1) {
#pragma unroll
        for (int nt = 0; nt < 4; nt++) {
            sA[nt] += __shfl_xor(sA[nt], o, 64);
            sB[nt] += __shfl_xor(sB[nt], o, 64);
        }
    }
    if (kq == 0) {
        float* pp = part_out + (blockIdx.x & (NSLICE - 1)) * 128;
#pragma unroll
        for (int nt = 0; nt < 4; nt++) {
            atomicAdd(&pp[nt * 16 + nc], sA[nt]);
            atomicAdd(&pp[64 + nt * 16 + nc], sB[nt]);
        }
    }
}

// ---------------------------------------------------------------------------
// Activation pass: act = f16(relu(h*sc+sh)), h stored f16, BN from partials.
__global__ __launch_bounds__(256) void k_act(const ushort* __restrict__ hraw,
                                             const float* __restrict__ part,
                                             const float* __restrict__ gamma,
                                             const float* __restrict__ beta,
                                             ushort* __restrict__ act, float invn) {
    __shared__ float st[128];
    __shared__ float sc[64], sh[64];
    int t = threadIdx.x;
    if (t < 128) {
        float S = 0.f;
#pragma unroll 8
        for (int s = 0; s < NSLICE; s++) S += part[s * 128 + t];
        st[t] = S;
    }
    __syncthreads();
    if (t < 64) {
        float mu = st[t] * invn;
        float var = fmaxf(st[64 + t] * invn - mu * mu, 0.f);
        float s = gamma[t] * rsqrtf(var + BN_EPS);
        sc[t] = s;
        sh[t] = beta[t] - mu * s;
    }
    __syncthreads();
    int base = (blockIdx.x * 256 + t) * 4;
    int f0 = base & 63;
    uint2 hv = *(const uint2*)(hraw + base);
    float a0 = fmaxf(fmaf(h_lo(hv.x), sc[f0 + 0], sh[f0 + 0]), 0.f);
    float a1 = fmaxf(fmaf(h_hi(hv.x), sc[f0 + 1], sh[f0 + 1]), 0.f);
    float a2 = fmaxf(fmaf(h_lo(hv.y), sc[f0 + 2], sh[f0 + 2]), 0.f);
    float a3 = fmaxf(fmaf(h_hi(hv.y), sc[f0 + 3], sh[f0 + 3]), 0.f);
    uint2 o;
    o.x = packh2(a0, a1);
    o.y = packh2(a2, a3);
    *(uint2*)(act + base) = o;
}

// ---------------------------------------------------------------------------
// Layers 1/2: REVERTED to the R0/R1-verified VALU gather (66.8 us measured
// twice), adapted to f16 act (h_lo/h_hi unpack). Rationale: four structurally
// different implementations (VALU gather / MFMA+u16 / MFMA+tr-read /
// chunk-pipelined) all pin the L2-miss path at 2.3-2.6 TB/s; the VALU
// version is the fastest of the four and sits ~8% above the compulsory
// cross-XCD traffic floor (~120 MB/layer at ~2.5 TB/s). MFMA variants lose
// on the serial gather->stage->read chain, and the compiler defeats both
// register-resident row pipelines (R0: VGPR cap; R7: rotation collapse).
// Block = 4 waves = 64 nodes; gather64 2 nodes/wave x 8 rounds, depth-3 col
// prefetch; per-wave f16 MFMA MLP + stats + f16 store.
__global__ __launch_bounds__(256, 4) void k_layerM(const uint* __restrict__ actin,
                                                   const int2* __restrict__ nodeoff,
                                                   const int* __restrict__ col,
                                                   const float* __restrict__ epsp,
                                                   const ushort* __restrict__ W1t,
                                                   const float* __restrict__ b1,
                                                   const ushort* __restrict__ W2t,
                                                   const float* __restrict__ b2,
                                                   ushort* __restrict__ hraw,
                                                   float* __restrict__ part_out) {
    __shared__ half_t buf[4][16][72];   // comb then h1 (aliased, wave-private)
    int t = threadIdx.x, w = t >> 6, lane = t & 63;
    int base = blockIdx.x * 64 + w * 16;
    float ep = 1.f + *epsp;
    int hl = lane >> 5, l5 = lane & 31;
    int q = l5 & 7, g = l5 >> 3;  // 4 groups x 8 lanes per half
    const uint4* hb4 = (const uint4*)actin;

    int nj = base + (lane & 15);
    int2 no2 = nodeoff[nj];  // padded past N (zero-init)
    bool njv = nj < N_NODES;
    int myStart = njv ? no2.x : 0;
    int myDeg = njv ? no2.y : 0;

    int stC, dgC, mxC, wvC, wv2C;
    int stN, dgN, mxN, wvN, wv2N;
    FETCH_COLS(0, stC, dgC, mxC, wvC, wv2C);
    FETCH_COLS(1, stN, dgN, mxN, wvN, wv2N);

    for (int r = 0; r < 8; r++) {
        int stNN, dgNN, mxNN, wvNN, wv2NN;
        FETCH_COLS(min(r + 2, 7), stNN, dgNN, mxNN, wvNN, wv2NN);
        int deg = dgC;
        float acc[8];
#pragma unroll
        for (int k = 0; k < 8; k++) acc[k] = 0.f;
        auto procm = [&](uint4 v, float m) {
            acc[0] = fmaf(m, h_lo(v.x), acc[0]);
            acc[1] = fmaf(m, h_hi(v.x), acc[1]);
            acc[2] = fmaf(m, h_lo(v.y), acc[2]);
            acc[3] = fmaf(m, h_hi(v.y), acc[3]);
            acc[4] = fmaf(m, h_lo(v.z), acc[4]);
            acc[5] = fmaf(m, h_hi(v.z), acc[5]);
            acc[6] = fmaf(m, h_lo(v.w), acc[6]);
            acc[7] = fmaf(m, h_hi(v.w), acc[7]);
        };
        if (mxC > 0) {
            int idx[8];
#pragma unroll
            for (int i = 0; i < 8; i++) idx[i] = __shfl(wvC, (hl << 5) + g + 4 * i, 64);
            uint4 rows[8];
#pragma unroll
            for (int i = 0; i < 8; i++) rows[i] = hb4[(size_t)idx[i] * 8 + q];
#pragma unroll
            for (int i = 0; i < 8; i++) procm(rows[i], (g + 4 * i < deg) ? 1.f : 0.f);
            if (mxC > 32) {
                int idx2[8];
#pragma unroll
                for (int i = 0; i < 8; i++) idx2[i] = __shfl(wv2C, (hl << 5) + g + 4 * i, 64);
                uint4 rows2[8];
#pragma unroll
                for (int i = 0; i < 8; i++) rows2[i] = hb4[(size_t)idx2[i] * 8 + q];
#pragma unroll
                for (int i = 0; i < 8; i++) procm(rows2[i], (32 + g + 4 * i < deg) ? 1.f : 0.f);
                for (int e = 64 + g; e < deg; e += 4)
                    procm(hb4[(size_t)col[stC + e] * 8 + q], 1.f);
            }
        }
#pragma unroll
        for (int o = 8; o < 32; o <<= 1) {
#pragma unroll
            for (int k = 0; k < 8; k++) acc[k] += __shfl_xor(acc[k], o, 64);
        }
        int node = base + 2 * r + hl;
        bool valid = node < N_NODES;
        int nodeC = valid ? node : 0;
        float vm = valid ? ep : 0.f;
        uint4 v = hb4[(size_t)nodeC * 8 + q];
        acc[0] = fmaf(vm, h_lo(v.x), acc[0]);
        acc[1] = fmaf(vm, h_hi(v.x), acc[1]);
        acc[2] = fmaf(vm, h_lo(v.y), acc[2]);
        acc[3] = fmaf(vm, h_hi(v.y), acc[3]);
        acc[4] = fmaf(vm, h_lo(v.z), acc[4]);
        acc[5] = fmaf(vm, h_hi(v.z), acc[5]);
        acc[6] = fmaf(vm, h_lo(v.w), acc[6]);
        acc[7] = fmaf(vm, h_hi(v.w), acc[7]);
        if (!valid) {
#pragma unroll
            for (int k = 0; k < 8; k++) acc[k] = 0.f;
        }
        if (g == 0) {
            int nl = 2 * r + hl;
            *(uint2*)&buf[w][nl][q * 8 + 0] = uint2{packh2(acc[0], acc[1]), packh2(acc[2], acc[3])};
            *(uint2*)&buf[w][nl][q * 8 + 4] = uint2{packh2(acc[4], acc[5]), packh2(acc[6], acc[7])};
        }
        stC = stN; dgC = dgN; mxC = mxN; wvC = wvN; wv2C = wv2N;
        stN = stNN; dgN = dgNN; mxN = mxNN; wvN = wvNN; wv2N = wv2NN;
    }
    // ---- f16 MFMA MLP (wave-synchronous LDS; no barrier; buf aliased) ----
    int mr = lane & 15, kq = lane >> 4, nc = lane & 15;
    h8v A0 = loadHh(&buf[w][mr][kq * 8]);
    h8v A1 = loadHh(&buf[w][mr][32 + kq * 8]);
#pragma unroll
    for (int nt = 0; nt < 4; nt++) {
        float bb = b1[nt * 16 + nc];
        f4v c = {bb, bb, bb, bb};
        c = mfma16(A0, loadH(W1t + (nt * 16 + nc) * 64 + kq * 8), c);
        c = mfma16(A1, loadH(W1t + (nt * 16 + nc) * 64 + 32 + kq * 8), c);
#pragma unroll
        for (int r2 = 0; r2 < 4; r2++)
            buf[w][kq * 4 + r2][nt * 16 + nc] = (half_t)fmaxf(c[r2], 0.f);
    }
    h8v P0 = loadHh(&buf[w][mr][kq * 8]);
    h8v P1 = loadHh(&buf[w][mr][32 + kq * 8]);
    float sA[4], sB[4];
#pragma unroll
    for (int nt = 0; nt < 4; nt++) { sA[nt] = 0.f; sB[nt] = 0.f; }
#pragma unroll
    for (int nt = 0; nt < 4; nt++) {
        float bb = b2[nt * 16 + nc];
        f4v c = {bb, bb, bb, bb};
        c = mfma16(P0, loadH(W2t + (nt * 16 + nc) * 64 + kq * 8), c);
        c = mfma16(P1, loadH(W2t + (nt * 16 + nc) * 64 + 32 + kq * 8), c);
#pragma unroll
        for (int r2 = 0; r2 < 4; r2++) {
            int node = base + kq * 4 + r2;
            float vv = fmaxf(c[r2], 0.f);
            if (node < N_NODES) {
                sA[nt] += vv;
                sB[nt] = fmaf(vv, vv, sB[nt]);
                hraw[(size_t)node * 64 + nt * 16 + nc] = f2h(vv);
            }
        }
    }
#pragma unroll
    for (int o = 16; o < 64; o <<= 1) {
#pragma unroll
        for (int nt = 0; nt < 4; nt++) {
            sA[nt] += __shfl_xor(sA[nt], o, 64);
            sB[nt] += __shfl_xor(sB[nt], o, 64);
        }
    }
    if (kq == 0) {
        float* pp = part_out + (blockIdx.x & (NSLICE - 1)) * 128;
#pragma unroll
        for (int nt = 0; nt < 4; nt++) {
            atomicAdd(&pp[nt * 16 + nc], sA[nt]);
            atomicAdd(&pp[64 + nt * 16 + nc], sB[nt]);
        }
    }
}

// ---------------------------------------------------------------------------
// Final: fold BN2 partials; out[i] = bf + sum_j relu(h*sc+sh) * Wf[j]
__global__ __launch_bounds__(256) void k_out(const ushort* __restrict__ hraw,
                                             const float* __restrict__ part,
                                             const float* __restrict__ gamma,
                                             const float* __restrict__ beta,
                                             const float* __restrict__ Wf,
                                             const float* __restrict__ bfp,
                                             float* __restrict__ out, int n,
                                             float invn) {
    __shared__ float st[128];
    __shared__ float sc[64], sh[64];
    int t = threadIdx.x;
    if (t < 128) {
        float S = 0.f;
#pragma unroll 8
        for (int s = 0; s < NSLICE; s++) S += part[s * 128 + t];
        st[t] = S;
    }
    __syncthreads();
    if (t < 64) {
        float mu = st[t] * invn;
        float var = fmaxf(st[64 + t] * invn - mu * mu, 0.f);
        float s = gamma[t] * rsqrtf(var + BN_EPS);
        sc[t] = s;
        sh[t] = beta[t] - mu * s;
    }
    __syncthreads();
    int i = blockIdx.x * blockDim.x + threadIdx.x;
    if (i >= n) return;
    float acc = *bfp;
    const uint2* h2 = (const uint2*)(hraw + (size_t)i * 64);
#pragma unroll
    for (int qq = 0; qq < 16; qq++) {
        uint2 v = h2[qq];
        int j = qq * 4;
        acc = fmaf(fmaxf(fmaf(h_lo(v.x), sc[j + 0], sh[j + 0]), 0.f), Wf[j + 0], acc);
        acc = fmaf(fmaxf(fmaf(h_hi(v.x), sc[j + 1], sh[j + 1]), 0.f), Wf[j + 1], acc);
        acc = fmaf(fmaxf(fmaf(h_lo(v.y), sc[j + 2], sh[j + 2]), 0.f), Wf[j + 2], acc);
        acc = fmaf(fmaxf(fmaf(h_hi(v.y), sc[j + 3], sh[j + 3]), 0.f), Wf[j + 3], acc);
    }
    out[i] = acc;
}

// ---------------------------------------------------------------------------
extern "C" void kernel_launch(void* const* d_in, const int* in_sizes, int n_in,
                              void* d_out, int out_size, void* d_ws, size_t ws_size,
                              hipStream_t stream) {
    const float* x      = (const float*)d_in[0];
    const int*   lab    = (const int*)d_in[1];
    const int*   edge   = (const int*)d_in[2];  // [2][E]: src then dst
    const float* emb    = (const float*)d_in[3];
    const float* W1_0   = (const float*)d_in[4];
    const float* b1_0   = (const float*)d_in[5];
    const float* W2_0   = (const float*)d_in[6];
    const float* b2_0   = (const float*)d_in[7];
    const float* eps_0  = (const float*)d_in[8];
    const float* gamma_0= (const float*)d_in[9];
    const float* beta_0 = (const float*)d_in[10];
    const float* W1_s   = (const float*)d_in[11];
    const float* b1_s   = (const float*)d_in[12];
    const float* W2_s   = (const float*)d_in[13];
    const float* b2_s   = (const float*)d_in[14];
    const float* eps_s  = (const float*)d_in[15];
    const float* gamma_s= (const float*)d_in[16];
    const float* beta_s = (const float*)d_in[17];
    const float* Wf     = (const float*)d_in[18];
    const float* bf     = (const float*)d_in[19];

    const int N = N_NODES, E = N_EDGES;
    const int* srcp = edge;
    const int* dstp = edge + E;

    char* p = (char*)d_ws;
    auto alloc = [&](size_t bytes) {
        void* r = (void*)p;
        p += (bytes + 255) & ~(size_t)255;
        return r;
    };
    int* bucket  = (int*)alloc((size_t)NBLK * BCAP * 4);      // 14.0 MB
    int* col2    = (int*)alloc((size_t)NBLK * BCAP * 4);      // 14.0 MB
    int* gcur    = (int*)alloc((size_t)NBLK * CUR_PAD * 4);   // 50 KB
    int* nodeoff = (int*)alloc((size_t)(N + 64) * 8);         // padded for OOB reads
    ushort* hraw = (ushort*)alloc((size_t)N * 64 * 2);        // 12.8 MB (f16)
    ushort* act  = (ushort*)alloc((size_t)N * 64 * 2);        // 12.8 MB (f16)
    ushort* h0   = (ushort*)alloc((size_t)N * 16 * 2);        //  3.2 MB (f16)
    float* parts = (float*)alloc(3 * NSLICE * 128 * 4);       // 48 KB
    ushort* W0t  = (ushort*)alloc(64 * 32 * 2);
    ushort* W20t = (ushort*)alloc(4096 * 2);
    ushort* Wst  = (ushort*)alloc(2 * 8192 * 2);

    hipMemsetAsync(gcur, 0, (size_t)NBLK * CUR_PAD * 4, stream);
    hipMemsetAsync(parts, 0, 3 * NSLICE * 128 * 4, stream);
    hipMemsetAsync(nodeoff + 2 * (size_t)N, 0, 64 * 8, stream);  // zero pad tail

    const int TB = 256;
    const int gN = (N + TB - 1) / TB;
    const int gM = (N + 63) / 64;  // 1563 blocks, 64 nodes each
    const int gA = N * 64 / 1024;
    const float invn = 1.0f / (float)N;

    k_h0<<<gN, TB, 0, stream>>>(x, lab, emb, h0, W1_0, W2_0, W1_s, W2_s,
                                W0t, W20t, Wst, N);
    k_fill<<<NW, TB, 0, stream>>>(srcp, dstp, gcur, bucket);
    k_sort<<<NBLK, TB, 0, stream>>>(gcur, bucket, col2, (int2*)nodeoff, N);

    // ---- Layer 0 ----
    k_layer0M<<<gM, TB, 0, stream>>>(h0, (const int2*)nodeoff, col2, eps_0, W0t,
                                     b1_0, W20t, b2_0, hraw,
                                     parts + 0 * NSLICE * 128);
    k_act<<<gA, TB, 0, stream>>>(hraw, parts + 0 * NSLICE * 128, gamma_0, beta_0,
                                 act, invn);

    // ---- Layer 1 ----
    k_layerM<<<gM, TB, 0, stream>>>((const uint*)act, (const int2*)nodeoff, col2,
                                    eps_s + 0, Wst + 0 * 8192, b1_s + 0 * 64,
                                    Wst + 0 * 8192 + 4096, b2_s + 0 * 64,
                                    hraw, parts + 1 * NSLICE * 128);
    k_act<<<gA, TB, 0, stream>>>(hraw, parts + 1 * NSLICE * 128, gamma_s + 0 * 64,
                                 beta_s + 0 * 64, act, invn);

    // ---- Layer 2 ----
    k_layerM<<<gM, TB, 0, stream>>>((const uint*)act, (const int2*)nodeoff, col2,
                                    eps_s + 1, Wst + 1 * 8192, b1_s + 1 * 64,
                                    Wst + 1 * 8192 + 4096, b2_s + 1 * 64,
                                    hraw, parts + 2 * NSLICE * 128);

    // ---- Output (BN2 folded from partials) ----
    k_out<<<gN, TB, 0, stream>>>(hraw, parts + 2 * NSLICE * 128,
                                 gamma_s + 1 * 64, beta_s + 1 * 64, Wf, bf,
                                 (float*)d_out, N, invn);
}